// Round 8
// baseline (705.314 us; speedup 1.0000x reference)
//
#include <hip/hip_runtime.h>

#define NU 50000
#define NE 100000
#define NN 150000          // NU + NE
#define DD 64
#define EUI 1500000

#define TPB 256
#define NBLK 2048          // edge-stride hist block count
#define NXB 2344           // ceil(NN/64) xw tiles
#define NXH (NXB + NBLK)   // merged xw+hist grid (4392)
#define NBF2 9375          // NN/16: k_fused blocks (4 waves x 4 nodes each)
#define NSC 9375           // NN*DD/4/256: k_scale blocks (exact)

// workspace layout (units: 4-byte words)
#define XWB_OFF    0ull          // 4,800,000 words: xW in bf16 (row = 32 dwords)
#define CNT_OFF    4800000ull    // 150,000 u32: per-node degree (atomic rank)
#define SCAL_OFF   4950000ull    // [0] = sum(exp(logits)), atomic-accumulated
#define XWQ_OFF    4950004ull    // 2,400,000 words: xW in q7e4 (row = 16 dwords)
// Padded-CSR src slots live in d_out: node n's 64 int slots occupy exactly the
// 256 bytes of out row n. k_fused reads its own slots, then overwrites them
// with the result row. Degrees are Binomial(1.5M, 1/150K): mean 10,
// P(deg>=64) ~ e^-150 -> the 64-slot stripe never overflows (guarded anyway).
// ROUND-4 LESSON: persistent cooperative fused+scale = 431 us (occupancy cap
// + ~115 us coop-launch overhead). Keep normal wide launches.
// ROUND-6 LESSON: 4-edge MLP unroll in k_fused = neutral -> fused is bound by
// gather transactions, not outstanding-load count.
// ROUND-7 LESSON: fp8 e4m3 gather rows fail absmax by 1.35x (5.59e-8 vs
// 4.14e-8 threshold) -- 3 mantissa bits is ~3-6% rel err, too coarse.
// Round-8: q7e4 block format (4x 7-bit mantissa + shared 4-bit exp per dword),
// ~4x more accurate at the same 64B row. Same 1-line-per-gather traffic plan.

// f32 -> bf16 RNE pack of two values into one dword (a = low/even dim)
__device__ __forceinline__ unsigned bfpack(float a, float b) {
  unsigned ua = __float_as_uint(a);
  ua = (ua + 0x7fffu + ((ua >> 16) & 1u)) >> 16;
  unsigned ub = __float_as_uint(b);
  ub = (ub + 0x7fffu + ((ub >> 16) & 1u)) & 0xffff0000u;
  return (ua & 0xffffu) | ub;
}

// ---- q7e4: 4 values -> 4x7-bit two's-complement mantissa + 4-bit shared exp.
// scale = 2^E, E = clamp(ilogb(quadmax)-5, -20, -5), field = E+20 in [0,15].
// quadmax/2^E in [32,64) -> |q| <= 64 (clamped to [-64,63]); abs err <=
// quadmax/64 (worst ~1.6% of quadmax, typ ~0.8%). xW entries ~N(0,0.125):
// quadmax < 1 << 63*2^-5=1.97, so the E=-5 clamp never saturates in practice.
__device__ __forceinline__ unsigned q7pack4(float a, float b, float c, float d) {
  const float m = fmaxf(fmaxf(fabsf(a), fabsf(b)), fmaxf(fabsf(c), fabsf(d)));
  int E = -20;
  if (m >= 3.0517578125e-05f) {   // 2^-15: below this, abs err < 2^-21 anyway
    E = (int)((__float_as_uint(m) >> 23) & 0xffu) - 132;  // ilogb(m) - 5
    E = max(-20, min(-5, E));
  }
  const float s = __uint_as_float((unsigned)(127 - E) << 23);  // 2^-E
  const int qa = max(-64, min(63, (int)rintf(a * s)));
  const int qb = max(-64, min(63, (int)rintf(b * s)));
  const int qc = max(-64, min(63, (int)rintf(c * s)));
  const int qd = max(-64, min(63, (int)rintf(d * s)));
  return ((unsigned)(E + 20) << 28) |
         (unsigned)(qa & 0x7f) | ((unsigned)(qb & 0x7f) << 7) |
         ((unsigned)(qc & 0x7f) << 14) | ((unsigned)(qd & 0x7f) << 21);
}

// decode: raw integer mantissas as floats + the shared scale (NOT pre-applied:
// the caller folds s into the dot result and into w -- 2 muls instead of 4).
__device__ __forceinline__ void q7unpack4(unsigned v, float& s, float& a,
                                          float& b, float& c, float& d) {
  s = __uint_as_float(((v >> 28) + 107u) << 23);   // 2^(field-20)
  a = (float)((int)(v << 25) >> 25);               // v_bfe_i32 pattern
  b = (float)((int)(v << 18) >> 25);
  c = (float)((int)(v << 11) >> 25);
  d = (float)((int)(v << 4) >> 25);
}

// x + dpp_perm(x) on the VALU pipe (no LDS/ds ops). ctrl must be an
// immediate -> template parameter.
template <int CTRL>
__device__ __forceinline__ float dpp_add(float x) {
  int y = __builtin_amdgcn_update_dpp(0, __float_as_int(x), CTRL, 0xF, 0xF, false);
  return x + __int_as_float(y);
}
// full sum across a 16-lane DPP row: +ror4, +ror8 (stride-4 class sums),
// then quad_perm xor1, xor2 (complete within-quad).
__device__ __forceinline__ float row16_sum(float x) {
  x = dpp_add<0x124>(x);  // row_ror:4
  x = dpp_add<0x128>(x);  // row_ror:8
  x = dpp_add<0xB1>(x);   // quad_perm [1,0,3,2]  (xor 1)
  x = dpp_add<0x4E>(x);   // quad_perm [2,3,0,1]  (xor 2)
  return x;
}

// ---------------- merged xW GEMM + hist + direct padded scatter ---------------
// Even blocks (first 2*NBLK) = GEMM tile, odd = hist stripe, remainder = GEMM.
// The 1.5M fabric RMWs (~64 us, scope-independent -- round-2 A/B) plus the
// 1.5M scattered slot stores (~37 us -- round-3 delta) are the transaction-
// rate wall of this kernel; the GEMM (and its q7e4 side-store) rides under it.
__global__ __launch_bounds__(TPB) void k_xw_hist(const int* __restrict__ uidx,
                                                 const int* __restrict__ iidx,
                                                 const float* __restrict__ ut,
                                                 const float* __restrict__ et,
                                                 const float* __restrict__ W,
                                                 unsigned* __restrict__ xwb,
                                                 unsigned* __restrict__ xwq,
                                                 const int* __restrict__ ei,
                                                 unsigned* __restrict__ cnt,
                                                 int* __restrict__ ssrcp) {
  const int bi = blockIdx.x;
  int idx;
  bool hist;
  if (bi < 2 * NBLK) { hist = (bi & 1); idx = bi >> 1; }
  else               { hist = false;    idx = bi - NBLK; }

  if (hist) {
    for (int e = idx * TPB + threadIdx.x; e < EUI; e += NBLK * TPB) {
      const int dst = ei[EUI + e];
      const int src = ei[e];
      const unsigned r = atomicAdd(&cnt[dst], 1u);
      if (r < 64u) ssrcp[((size_t)dst << 6) + r] = src;
    }
    return;  // uniform per block: no thread reaches __syncthreads below
  }

  // -------- xW = concat(user_table[uidx], entity_table[iidx]) @ W --------
  // LDS-tiled 64x64x64 f32 GEMM; kc loop deliberately NOT unrolled (full
  // unroll hoisted all 64 ds_read_b128 -> VGPR 232, occupancy 10%).
  __shared__ float Ws[DD * DD];   // [k][c]
  __shared__ float Xs[64 * 68];   // [r][k], padded stride 68
  const int t = threadIdx.x;
  {
    const float4* W4 = (const float4*)W;
    float4* Ws4 = (float4*)Ws;
#pragma unroll
    for (int i = 0; i < 4; ++i) Ws4[t + i * TPB] = W4[t + i * TPB];
  }
  {
    const int rl = t >> 2, ch = t & 3;   // 4 threads per row, 4 float4 each
    int row = idx * 64 + rl;
    if (row >= NN) row = NN - 1;         // clamp; stores guarded below
    const float4* s4 = (const float4*)((row < NU)
        ? ut + (size_t)uidx[row] * DD
        : et + (size_t)iidx[row - NU] * DD);
    float4* x4 = (float4*)(Xs + rl * 68);
#pragma unroll
    for (int j = 0; j < 4; ++j) x4[ch + 4 * j] = s4[ch + 4 * j];
  }
  __syncthreads();
  const int q = t & 15, g = t >> 4;      // col quad, row group (4 rows)
  float4 acc[4] = {{0,0,0,0},{0,0,0,0},{0,0,0,0},{0,0,0,0}};
  const float* __restrict__ wsq = Ws + 4 * q;
  const float* __restrict__ xsg = Xs + (4 * g) * 68;
#pragma unroll 1
  for (int kc = 0; kc < 16; ++kc) {
    const float4 w0 = *(const float4*)(wsq + (4 * kc + 0) * DD);
    const float4 w1 = *(const float4*)(wsq + (4 * kc + 1) * DD);
    const float4 w2 = *(const float4*)(wsq + (4 * kc + 2) * DD);
    const float4 w3 = *(const float4*)(wsq + (4 * kc + 3) * DD);
#pragma unroll
    for (int i = 0; i < 4; ++i) {
      const float4 x = *(const float4*)(xsg + i * 68 + 4 * kc);
      acc[i].x = fmaf(x.x, w0.x, acc[i].x);
      acc[i].y = fmaf(x.x, w0.y, acc[i].y);
      acc[i].z = fmaf(x.x, w0.z, acc[i].z);
      acc[i].w = fmaf(x.x, w0.w, acc[i].w);
      acc[i].x = fmaf(x.y, w1.x, acc[i].x);
      acc[i].y = fmaf(x.y, w1.y, acc[i].y);
      acc[i].z = fmaf(x.y, w1.z, acc[i].z);
      acc[i].w = fmaf(x.y, w1.w, acc[i].w);
      acc[i].x = fmaf(x.z, w2.x, acc[i].x);
      acc[i].y = fmaf(x.z, w2.y, acc[i].y);
      acc[i].z = fmaf(x.z, w2.z, acc[i].z);
      acc[i].w = fmaf(x.z, w2.w, acc[i].w);
      acc[i].x = fmaf(x.w, w3.x, acc[i].x);
      acc[i].y = fmaf(x.w, w3.y, acc[i].y);
      acc[i].z = fmaf(x.w, w3.z, acc[i].z);
      acc[i].w = fmaf(x.w, w3.w, acc[i].w);
    }
  }
#pragma unroll
  for (int i = 0; i < 4; ++i) {
    const int row = idx * 64 + 4 * g + i;
    if (row < NN) {
      uint2 p;
      p.x = bfpack(acc[i].x, acc[i].y);
      p.y = bfpack(acc[i].z, acc[i].w);
      ((uint2*)(xwb + (size_t)row * 32))[q] = p;
      xwq[(size_t)row * 16 + q] = q7pack4(acc[i].x, acc[i].y, acc[i].z, acc[i].w);
    }
  }
}

// ---------------- fused logits+exp+aggregate (q7e4 gather, DPP reduce) --------
// 16 lanes per node, 4 nodes per wave, 4 edges per group per iteration.
// Src rows gathered from the q7e4 side-copy (64B row = 1 cache line; 9.6 MB
// working set -> ~2x per-XCD L2 hit fraction); dst row stays bf16. The shared
// scale folds into the dot result (p *= s) and the weight (ws = w*s), so the
// inner math runs on raw integer mantissas as floats.
// Block exp-partials atomicAdd straight into scal (no k_rsum).
// ssrcp and out alias (same buffer): node n's slots are exactly out row n;
// all slot reads for n precede the single row-n store. No __restrict__.
__global__ __launch_bounds__(TPB) void k_fused(const unsigned* __restrict__ cnt,
                                               const int* ssrcp,
                                               const unsigned* __restrict__ xwb,
                                               const unsigned* __restrict__ xwq,
                                               float* out,
                                               float* __restrict__ scal) {
  const int lane = threadIdx.x & 63;
  const int wv = threadIdx.x >> 6;
  const int sub = lane >> 4;   // node slot 0..3 (DPP row)
  const int q = lane & 15;     // dim quad 0..15
  const int n = blockIdx.x * 16 + wv * 4 + sub;  // < NN (NN == 16*NBF2)
  const uint2* __restrict__ x2 = (const uint2*)xwb;  // bf16 row = 16 uint2
  const uint2 dv = x2[(size_t)n * 16 + q];
  const float vd0 = __uint_as_float(dv.x << 16);
  const float vd1 = __uint_as_float(dv.x & 0xffff0000u);
  const float vd2 = __uint_as_float(dv.y << 16);
  const float vd3 = __uint_as_float(dv.y & 0xffff0000u);
  const int deg = min((int)cnt[n], 64);
  int dmax = deg;                                   // wave-uniform max degree
  dmax = max(dmax, __shfl_xor(dmax, 16, 64));
  dmax = max(dmax, __shfl_xor(dmax, 32, 64));
  const size_t base = (size_t)n << 6;
  const int nit = (dmax + 3) >> 2;                  // 4 edges / iteration
  float a0 = 0.f, a1 = 0.f, a2 = 0.f, a3 = 0.f, wacc = 0.f;
  // prefetched slot quad (indices <= 4*nit-1 <= 63: in-stripe)
  int sl0 = ssrcp[base], sl1 = ssrcp[base + 1];
  int sl2 = ssrcp[base + 2], sl3 = ssrcp[base + 3];
  for (int ii = 0; ii < nit; ++ii) {
    const int it = 4 * ii;
    int s0 = sl0, s1 = sl1, s2 = sl2, s3 = sl3;
    if (ii + 1 < nit) {
      sl0 = ssrcp[base + it + 4];
      sl1 = ssrcp[base + it + 5];
      sl2 = ssrcp[base + it + 6];
      sl3 = ssrcp[base + it + 7];
    }
    const bool act0 = it < deg;
    const bool act1 = it + 1 < deg;
    const bool act2 = it + 2 < deg;
    const bool act3 = it + 3 < deg;
    if (!act0) s0 = 0;   // sanitize BEFORE gather: padding is uninitialized
    if (!act1) s1 = 0;
    if (!act2) s2 = 0;
    if (!act3) s3 = 0;
    const unsigned sv0 = xwq[(size_t)s0 * 16 + q];  // 4 independent 1-line gathers
    const unsigned sv1 = xwq[(size_t)s1 * 16 + q];
    const unsigned sv2 = xwq[(size_t)s2 * 16 + q];
    const unsigned sv3 = xwq[(size_t)s3 * 16 + q];
    float se0, u0, u1, u2, u3;
    float se1, t0, t1, t2, t3;
    float se2, g0, g1, g2, g3;
    float se3, h0, h1, h2, h3;
    q7unpack4(sv0, se0, u0, u1, u2, u3);
    q7unpack4(sv1, se1, t0, t1, t2, t3);
    q7unpack4(sv2, se2, g0, g1, g2, g3);
    q7unpack4(sv3, se3, h0, h1, h2, h3);
    float p0 = vd0 * u0;
    p0 = fmaf(vd1, u1, p0); p0 = fmaf(vd2, u2, p0); p0 = fmaf(vd3, u3, p0);
    float p1 = vd0 * t0;
    p1 = fmaf(vd1, t1, p1); p1 = fmaf(vd2, t2, p1); p1 = fmaf(vd3, t3, p1);
    float p2 = vd0 * g0;
    p2 = fmaf(vd1, g1, p2); p2 = fmaf(vd2, g2, p2); p2 = fmaf(vd3, g3, p2);
    float p3 = vd0 * h0;
    p3 = fmaf(vd1, h1, p3); p3 = fmaf(vd2, h2, p3); p3 = fmaf(vd3, h3, p3);
    p0 *= se0;                 // apply shared scale once per dot
    p1 *= se1;
    p2 *= se2;
    p3 *= se3;
    p0 = row16_sum(p0);
    p1 = row16_sum(p1);
    p2 = row16_sum(p2);
    p3 = row16_sum(p3);
    const float l0 = (p0 > 0.f) ? p0 : 0.2f * p0;
    const float l1 = (p1 > 0.f) ? p1 : 0.2f * p1;
    const float l2 = (p2 > 0.f) ? p2 : 0.2f * p2;
    const float l3 = (p3 > 0.f) ? p3 : 0.2f * p3;
    float w0 = __expf(l0);
    float w1 = __expf(l1);
    float w2 = __expf(l2);
    float w3 = __expf(l3);
    if (!act0) w0 = 0.f;
    if (!act1) w1 = 0.f;
    if (!act2) w2 = 0.f;
    if (!act3) w3 = 0.f;
    const float ws0 = w0 * se0;   // fold scale into the weight for aggregation
    const float ws1 = w1 * se1;
    const float ws2 = w2 * se2;
    const float ws3 = w3 * se3;
    a0 = fmaf(ws0, u0, a0); a1 = fmaf(ws0, u1, a1);
    a2 = fmaf(ws0, u2, a2); a3 = fmaf(ws0, u3, a3);
    a0 = fmaf(ws1, t0, a0); a1 = fmaf(ws1, t1, a1);
    a2 = fmaf(ws1, t2, a2); a3 = fmaf(ws1, t3, a3);
    a0 = fmaf(ws2, g0, a0); a1 = fmaf(ws2, g1, a1);
    a2 = fmaf(ws2, g2, a2); a3 = fmaf(ws2, g3, a3);
    a0 = fmaf(ws3, h0, a0); a1 = fmaf(ws3, h1, a1);
    a2 = fmaf(ws3, h2, a2); a3 = fmaf(ws3, h3, a3);
    wacc += (w0 + w1) + (w2 + w3);   // group-uniform (same w on all 16 lanes)
  }
  float4 r = {a0, a1, a2, a3};
  ((float4*)(out + (size_t)n * DD))[q] = r;   // overwrites this node's slots
  // block partial of sum(exp) -> one device atomicAdd per block
  __shared__ float sm[16];
  if (q == 0) sm[wv * 4 + sub] = wacc;
  __syncthreads();
  if (threadIdx.x == 0) {
    float s = 0.f;
#pragma unroll
    for (int i = 0; i < 16; ++i) s += sm[i];
    atomicAdd(scal, s);
  }
}

// ---------------- out = relu(out / sumexp) ------------------------------------
__global__ __launch_bounds__(TPB) void k_scale(float* __restrict__ out,
                                               const float* __restrict__ scal) {
  const float inv = 1.0f / scal[0];
  const int i = blockIdx.x * TPB + threadIdx.x;
  float4* o4 = (float4*)out;
  float4 v = o4[i];
  v.x = fmaxf(v.x * inv, 0.f);
  v.y = fmaxf(v.y * inv, 0.f);
  v.z = fmaxf(v.z * inv, 0.f);
  v.w = fmaxf(v.w * inv, 0.f);
  o4[i] = v;
}

extern "C" void kernel_launch(void* const* d_in, const int* in_sizes, int n_in,
                              void* d_out, int out_size, void* d_ws, size_t ws_size,
                              hipStream_t stream) {
  const int* uidx = (const int*)d_in[0];
  const int* iidx = (const int*)d_in[1];
  const int* ei_ui = (const int*)d_in[2];
  // d_in[3], d_in[4], d_in[8] (KG graph, W_r): dead code in the reference
  // (x_kg is added into x, then x is fully overwritten by relu(x_ui)).
  const float* ut = (const float*)d_in[5];
  const float* et = (const float*)d_in[6];
  const float* W = (const float*)d_in[7];

  float* out = (float*)d_out;
  float* ws = (float*)d_ws;
  unsigned* xwb = (unsigned*)(ws + XWB_OFF);
  unsigned* cnt = (unsigned*)(ws + CNT_OFF);
  float* scal = ws + SCAL_OFF;
  unsigned* xwq = (unsigned*)(ws + XWQ_OFF);
  int* ssrcp = (int*)d_out;   // padded-CSR slots, aliased with out (see k_fused)

  // clears cnt (150,000 u32) AND scal (adjacent word) in one memset
  (void)hipMemsetAsync(cnt, 0, (size_t)(NN + 1) * sizeof(unsigned), stream);

  k_xw_hist<<<NXH, TPB, 0, stream>>>(uidx, iidx, ut, et, W, xwb, xwq, ei_ui,
                                     cnt, ssrcp);
  k_fused<<<NBF2, TPB, 0, stream>>>(cnt, ssrcp, xwb, xwq, out, scal);
  k_scale<<<NSC, TPB, 0, stream>>>(out, scal);
}

// Round 9
// 263.148 us; speedup vs baseline: 2.6803x; 2.6803x over previous
//
#include <hip/hip_runtime.h>

#define NU 50000
#define NE 100000
#define NN 150000          // NU + NE
#define DD 64
#define EUI 1500000

#define TPB 256
#define NBLK 2048          // edge-stride hist block count
#define NXB 2344           // ceil(NN/64) xw tiles
#define NXH (NXB + NBLK)   // merged xw+hist grid (4392)
#define NBF2 9375          // NN/16: k_fused blocks (4 waves x 4 nodes each)
#define NSC 9375           // NN*DD/4/256: k_scale blocks (exact)

// workspace layout (units: 4-byte words)
#define XWB_OFF    0ull          // 4,800,000 words: xW in bf16 (row = 32 dwords)
#define CNT_OFF    4800000ull    // 150,000 u32: per-node degree (atomic rank)
#define SCAL_OFF   4950000ull    // [0] = sum(exp(logits))
#define PSUM_OFF   4950004ull    // 9,375 f32 block partials
#define XWQ_OFF    4959424ull    // 2,400,000 words: xW in q7e4 (row = 16 dwords)
                                 // byte addr 19,837,696 % 64 == 0: one row = ONE
                                 // cache line (round-8 had it %64==16 -> 2 lines)
// Padded-CSR src slots live in d_out: node n's 64 int slots occupy exactly the
// 256 bytes of out row n. k_fused reads its own slots, then overwrites them
// with the result row. Degrees are Binomial(1.5M, 1/150K): mean 10,
// P(deg>=64) ~ e^-150 -> the 64-slot stripe never overflows (guarded anyway).
// ROUND-4 LESSON: persistent cooperative fused+scale = 431 us (occupancy cap
// + ~115 us coop-launch overhead). Keep normal wide launches.
// ROUND-6 LESSON: 4-edge MLP unroll in k_fused = neutral -> fused is bound by
// gather transactions, not outstanding-load count.
// ROUND-7 LESSON: fp8 e4m3 fails absmax by 1.35x; q7e4 (7-bit mantissa,
// shared exp) passes with 2.2x margin (round 8: 1.86e-8 vs 4.14e-8).
// ROUND-8 LESSON: 9375 same-address device atomicAdd(scal) = ~53 ns EACH,
// fully serialized (503 us kernel, everything idle). NEVER funnel per-block
// results through one address; psum[] array + k_rsum costs ~5 us total.
// Round-9: q7e4 gather retained, xwq 64B-aligned, psum/k_rsum tail restored.

// f32 -> bf16 RNE pack of two values into one dword (a = low/even dim)
__device__ __forceinline__ unsigned bfpack(float a, float b) {
  unsigned ua = __float_as_uint(a);
  ua = (ua + 0x7fffu + ((ua >> 16) & 1u)) >> 16;
  unsigned ub = __float_as_uint(b);
  ub = (ub + 0x7fffu + ((ub >> 16) & 1u)) & 0xffff0000u;
  return (ua & 0xffffu) | ub;
}

// ---- q7e4: 4 values -> 4x7-bit two's-complement mantissa + 4-bit shared exp.
// scale = 2^E, E = clamp(ilogb(quadmax)-5, -20, -5), field = E+20 in [0,15].
// abs err <= quadmax/64 (typ ~0.8% of quadmax) -- ~4x better than fp8 e4m3.
__device__ __forceinline__ unsigned q7pack4(float a, float b, float c, float d) {
  const float m = fmaxf(fmaxf(fabsf(a), fabsf(b)), fmaxf(fabsf(c), fabsf(d)));
  int E = -20;
  if (m >= 3.0517578125e-05f) {   // 2^-15: below this, abs err < 2^-21 anyway
    E = (int)((__float_as_uint(m) >> 23) & 0xffu) - 132;  // ilogb(m) - 5
    E = max(-20, min(-5, E));
  }
  const float s = __uint_as_float((unsigned)(127 - E) << 23);  // 2^-E
  const int qa = max(-64, min(63, (int)rintf(a * s)));
  const int qb = max(-64, min(63, (int)rintf(b * s)));
  const int qc = max(-64, min(63, (int)rintf(c * s)));
  const int qd = max(-64, min(63, (int)rintf(d * s)));
  return ((unsigned)(E + 20) << 28) |
         (unsigned)(qa & 0x7f) | ((unsigned)(qb & 0x7f) << 7) |
         ((unsigned)(qc & 0x7f) << 14) | ((unsigned)(qd & 0x7f) << 21);
}

// decode: raw integer mantissas as floats + the shared scale (NOT pre-applied:
// the caller folds s into the dot result and into w -- 2 muls instead of 4).
__device__ __forceinline__ void q7unpack4(unsigned v, float& s, float& a,
                                          float& b, float& c, float& d) {
  s = __uint_as_float(((v >> 28) + 107u) << 23);   // 2^(field-20)
  a = (float)((int)(v << 25) >> 25);               // v_bfe_i32 pattern
  b = (float)((int)(v << 18) >> 25);
  c = (float)((int)(v << 11) >> 25);
  d = (float)((int)(v << 4) >> 25);
}

// x + dpp_perm(x) on the VALU pipe (no LDS/ds ops). ctrl must be an
// immediate -> template parameter.
template <int CTRL>
__device__ __forceinline__ float dpp_add(float x) {
  int y = __builtin_amdgcn_update_dpp(0, __float_as_int(x), CTRL, 0xF, 0xF, false);
  return x + __int_as_float(y);
}
// full sum across a 16-lane DPP row: +ror4, +ror8 (stride-4 class sums),
// then quad_perm xor1, xor2 (complete within-quad).
__device__ __forceinline__ float row16_sum(float x) {
  x = dpp_add<0x124>(x);  // row_ror:4
  x = dpp_add<0x128>(x);  // row_ror:8
  x = dpp_add<0xB1>(x);   // quad_perm [1,0,3,2]  (xor 1)
  x = dpp_add<0x4E>(x);   // quad_perm [2,3,0,1]  (xor 2)
  return x;
}

// ---------------- merged xW GEMM + hist + direct padded scatter ---------------
// Even blocks (first 2*NBLK) = GEMM tile, odd = hist stripe, remainder = GEMM.
// The 1.5M fabric RMWs (~64 us, scope-independent -- round-2 A/B) plus the
// 1.5M scattered slot stores (~37 us -- round-3 delta) are the transaction-
// rate wall of this kernel; the GEMM (and its q7e4 side-store) rides under it.
__global__ __launch_bounds__(TPB) void k_xw_hist(const int* __restrict__ uidx,
                                                 const int* __restrict__ iidx,
                                                 const float* __restrict__ ut,
                                                 const float* __restrict__ et,
                                                 const float* __restrict__ W,
                                                 unsigned* __restrict__ xwb,
                                                 unsigned* __restrict__ xwq,
                                                 const int* __restrict__ ei,
                                                 unsigned* __restrict__ cnt,
                                                 int* __restrict__ ssrcp) {
  const int bi = blockIdx.x;
  int idx;
  bool hist;
  if (bi < 2 * NBLK) { hist = (bi & 1); idx = bi >> 1; }
  else               { hist = false;    idx = bi - NBLK; }

  if (hist) {
    for (int e = idx * TPB + threadIdx.x; e < EUI; e += NBLK * TPB) {
      const int dst = ei[EUI + e];
      const int src = ei[e];
      const unsigned r = atomicAdd(&cnt[dst], 1u);
      if (r < 64u) ssrcp[((size_t)dst << 6) + r] = src;
    }
    return;  // uniform per block: no thread reaches __syncthreads below
  }

  // -------- xW = concat(user_table[uidx], entity_table[iidx]) @ W --------
  // LDS-tiled 64x64x64 f32 GEMM; kc loop deliberately NOT unrolled (full
  // unroll hoisted all 64 ds_read_b128 -> VGPR 232, occupancy 10%).
  __shared__ float Ws[DD * DD];   // [k][c]
  __shared__ float Xs[64 * 68];   // [r][k], padded stride 68
  const int t = threadIdx.x;
  {
    const float4* W4 = (const float4*)W;
    float4* Ws4 = (float4*)Ws;
#pragma unroll
    for (int i = 0; i < 4; ++i) Ws4[t + i * TPB] = W4[t + i * TPB];
  }
  {
    const int rl = t >> 2, ch = t & 3;   // 4 threads per row, 4 float4 each
    int row = idx * 64 + rl;
    if (row >= NN) row = NN - 1;         // clamp; stores guarded below
    const float4* s4 = (const float4*)((row < NU)
        ? ut + (size_t)uidx[row] * DD
        : et + (size_t)iidx[row - NU] * DD);
    float4* x4 = (float4*)(Xs + rl * 68);
#pragma unroll
    for (int j = 0; j < 4; ++j) x4[ch + 4 * j] = s4[ch + 4 * j];
  }
  __syncthreads();
  const int q = t & 15, g = t >> 4;      // col quad, row group (4 rows)
  float4 acc[4] = {{0,0,0,0},{0,0,0,0},{0,0,0,0},{0,0,0,0}};
  const float* __restrict__ wsq = Ws + 4 * q;
  const float* __restrict__ xsg = Xs + (4 * g) * 68;
#pragma unroll 1
  for (int kc = 0; kc < 16; ++kc) {
    const float4 w0 = *(const float4*)(wsq + (4 * kc + 0) * DD);
    const float4 w1 = *(const float4*)(wsq + (4 * kc + 1) * DD);
    const float4 w2 = *(const float4*)(wsq + (4 * kc + 2) * DD);
    const float4 w3 = *(const float4*)(wsq + (4 * kc + 3) * DD);
#pragma unroll
    for (int i = 0; i < 4; ++i) {
      const float4 x = *(const float4*)(xsg + i * 68 + 4 * kc);
      acc[i].x = fmaf(x.x, w0.x, acc[i].x);
      acc[i].y = fmaf(x.x, w0.y, acc[i].y);
      acc[i].z = fmaf(x.x, w0.z, acc[i].z);
      acc[i].w = fmaf(x.x, w0.w, acc[i].w);
      acc[i].x = fmaf(x.y, w1.x, acc[i].x);
      acc[i].y = fmaf(x.y, w1.y, acc[i].y);
      acc[i].z = fmaf(x.y, w1.z, acc[i].z);
      acc[i].w = fmaf(x.y, w1.w, acc[i].w);
      acc[i].x = fmaf(x.z, w2.x, acc[i].x);
      acc[i].y = fmaf(x.z, w2.y, acc[i].y);
      acc[i].z = fmaf(x.z, w2.z, acc[i].z);
      acc[i].w = fmaf(x.z, w2.w, acc[i].w);
      acc[i].x = fmaf(x.w, w3.x, acc[i].x);
      acc[i].y = fmaf(x.w, w3.y, acc[i].y);
      acc[i].z = fmaf(x.w, w3.z, acc[i].z);
      acc[i].w = fmaf(x.w, w3.w, acc[i].w);
    }
  }
#pragma unroll
  for (int i = 0; i < 4; ++i) {
    const int row = idx * 64 + 4 * g + i;
    if (row < NN) {
      uint2 p;
      p.x = bfpack(acc[i].x, acc[i].y);
      p.y = bfpack(acc[i].z, acc[i].w);
      ((uint2*)(xwb + (size_t)row * 32))[q] = p;
      xwq[(size_t)row * 16 + q] = q7pack4(acc[i].x, acc[i].y, acc[i].z, acc[i].w);
    }
  }
}

// ---------------- fused logits+exp+aggregate (q7e4 gather, DPP reduce) --------
// 16 lanes per node, 4 nodes per wave, 4 edges per group per iteration.
// Src rows gathered from the 64B-ALIGNED q7e4 copy (1 cache line per edge;
// 9.6 MB working set); dst row read from bf16. Shared scale folds into the
// dot result (p *= s) and the weight (ws = w*s).
// Block exp-partials -> psum[] array (round-8 lesson: no same-address atomic).
// ssrcp and out alias (same buffer): node n's slots are exactly out row n;
// all slot reads for n precede the single row-n store. No __restrict__.
__global__ __launch_bounds__(TPB) void k_fused(const unsigned* __restrict__ cnt,
                                               const int* ssrcp,
                                               const unsigned* __restrict__ xwb,
                                               const unsigned* __restrict__ xwq,
                                               float* out,
                                               float* __restrict__ psum) {
  const int lane = threadIdx.x & 63;
  const int wv = threadIdx.x >> 6;
  const int sub = lane >> 4;   // node slot 0..3 (DPP row)
  const int q = lane & 15;     // dim quad 0..15
  const int n = blockIdx.x * 16 + wv * 4 + sub;  // < NN (NN == 16*NBF2)
  const uint2* __restrict__ x2 = (const uint2*)xwb;  // bf16 row = 16 uint2
  const uint2 dv = x2[(size_t)n * 16 + q];
  const float vd0 = __uint_as_float(dv.x << 16);
  const float vd1 = __uint_as_float(dv.x & 0xffff0000u);
  const float vd2 = __uint_as_float(dv.y << 16);
  const float vd3 = __uint_as_float(dv.y & 0xffff0000u);
  const int deg = min((int)cnt[n], 64);
  int dmax = deg;                                   // wave-uniform max degree
  dmax = max(dmax, __shfl_xor(dmax, 16, 64));
  dmax = max(dmax, __shfl_xor(dmax, 32, 64));
  const size_t base = (size_t)n << 6;
  const int nit = (dmax + 3) >> 2;                  // 4 edges / iteration
  float a0 = 0.f, a1 = 0.f, a2 = 0.f, a3 = 0.f, wacc = 0.f;
  // prefetched slot quad (indices <= 4*nit-1 <= 63: in-stripe)
  int sl0 = ssrcp[base], sl1 = ssrcp[base + 1];
  int sl2 = ssrcp[base + 2], sl3 = ssrcp[base + 3];
  for (int ii = 0; ii < nit; ++ii) {
    const int it = 4 * ii;
    int s0 = sl0, s1 = sl1, s2 = sl2, s3 = sl3;
    if (ii + 1 < nit) {
      sl0 = ssrcp[base + it + 4];
      sl1 = ssrcp[base + it + 5];
      sl2 = ssrcp[base + it + 6];
      sl3 = ssrcp[base + it + 7];
    }
    const bool act0 = it < deg;
    const bool act1 = it + 1 < deg;
    const bool act2 = it + 2 < deg;
    const bool act3 = it + 3 < deg;
    if (!act0) s0 = 0;   // sanitize BEFORE gather: padding is uninitialized
    if (!act1) s1 = 0;
    if (!act2) s2 = 0;
    if (!act3) s3 = 0;
    const unsigned sv0 = xwq[(size_t)s0 * 16 + q];  // 4 independent 1-line gathers
    const unsigned sv1 = xwq[(size_t)s1 * 16 + q];
    const unsigned sv2 = xwq[(size_t)s2 * 16 + q];
    const unsigned sv3 = xwq[(size_t)s3 * 16 + q];
    float se0, u0, u1, u2, u3;
    float se1, t0, t1, t2, t3;
    float se2, g0, g1, g2, g3;
    float se3, h0, h1, h2, h3;
    q7unpack4(sv0, se0, u0, u1, u2, u3);
    q7unpack4(sv1, se1, t0, t1, t2, t3);
    q7unpack4(sv2, se2, g0, g1, g2, g3);
    q7unpack4(sv3, se3, h0, h1, h2, h3);
    float p0 = vd0 * u0;
    p0 = fmaf(vd1, u1, p0); p0 = fmaf(vd2, u2, p0); p0 = fmaf(vd3, u3, p0);
    float p1 = vd0 * t0;
    p1 = fmaf(vd1, t1, p1); p1 = fmaf(vd2, t2, p1); p1 = fmaf(vd3, t3, p1);
    float p2 = vd0 * g0;
    p2 = fmaf(vd1, g1, p2); p2 = fmaf(vd2, g2, p2); p2 = fmaf(vd3, g3, p2);
    float p3 = vd0 * h0;
    p3 = fmaf(vd1, h1, p3); p3 = fmaf(vd2, h2, p3); p3 = fmaf(vd3, h3, p3);
    p0 *= se0;                 // apply shared scale once per dot
    p1 *= se1;
    p2 *= se2;
    p3 *= se3;
    p0 = row16_sum(p0);
    p1 = row16_sum(p1);
    p2 = row16_sum(p2);
    p3 = row16_sum(p3);
    const float l0 = (p0 > 0.f) ? p0 : 0.2f * p0;
    const float l1 = (p1 > 0.f) ? p1 : 0.2f * p1;
    const float l2 = (p2 > 0.f) ? p2 : 0.2f * p2;
    const float l3 = (p3 > 0.f) ? p3 : 0.2f * p3;
    float w0 = __expf(l0);
    float w1 = __expf(l1);
    float w2 = __expf(l2);
    float w3 = __expf(l3);
    if (!act0) w0 = 0.f;
    if (!act1) w1 = 0.f;
    if (!act2) w2 = 0.f;
    if (!act3) w3 = 0.f;
    const float ws0 = w0 * se0;   // fold scale into the weight for aggregation
    const float ws1 = w1 * se1;
    const float ws2 = w2 * se2;
    const float ws3 = w3 * se3;
    a0 = fmaf(ws0, u0, a0); a1 = fmaf(ws0, u1, a1);
    a2 = fmaf(ws0, u2, a2); a3 = fmaf(ws0, u3, a3);
    a0 = fmaf(ws1, t0, a0); a1 = fmaf(ws1, t1, a1);
    a2 = fmaf(ws1, t2, a2); a3 = fmaf(ws1, t3, a3);
    a0 = fmaf(ws2, g0, a0); a1 = fmaf(ws2, g1, a1);
    a2 = fmaf(ws2, g2, a2); a3 = fmaf(ws2, g3, a3);
    a0 = fmaf(ws3, h0, a0); a1 = fmaf(ws3, h1, a1);
    a2 = fmaf(ws3, h2, a2); a3 = fmaf(ws3, h3, a3);
    wacc += (w0 + w1) + (w2 + w3);   // group-uniform (same w on all 16 lanes)
  }
  float4 r = {a0, a1, a2, a3};
  ((float4*)(out + (size_t)n * DD))[q] = r;   // overwrites this node's slots
  // block partial of sum(exp): one lane per group (q==0) holds wacc
  __shared__ float sm[16];
  if (q == 0) sm[wv * 4 + sub] = wacc;
  __syncthreads();
  if (threadIdx.x == 0) {
    float s = 0.f;
#pragma unroll
    for (int i = 0; i < 16; ++i) s += sm[i];
    psum[blockIdx.x] = s;
  }
}

// ---------------- total exp-sum -----------------------------------------------
__global__ __launch_bounds__(TPB) void k_rsum(const float* __restrict__ psum,
                                              float* __restrict__ scal) {
  float s = 0.f;
  for (int i = threadIdx.x; i < NBF2; i += TPB) s += psum[i];
#pragma unroll
  for (int off = 32; off; off >>= 1) s += __shfl_xor(s, off, 64);
  __shared__ float sm[4];
  if ((threadIdx.x & 63) == 0) sm[threadIdx.x >> 6] = s;
  __syncthreads();
  if (threadIdx.x == 0) scal[0] = sm[0] + sm[1] + sm[2] + sm[3];
}

// ---------------- out = relu(out / sumexp) ------------------------------------
__global__ __launch_bounds__(TPB) void k_scale(float* __restrict__ out,
                                               const float* __restrict__ scal) {
  const float inv = 1.0f / scal[0];
  const int i = blockIdx.x * TPB + threadIdx.x;
  float4* o4 = (float4*)out;
  float4 v = o4[i];
  v.x = fmaxf(v.x * inv, 0.f);
  v.y = fmaxf(v.y * inv, 0.f);
  v.z = fmaxf(v.z * inv, 0.f);
  v.w = fmaxf(v.w * inv, 0.f);
  o4[i] = v;
}

extern "C" void kernel_launch(void* const* d_in, const int* in_sizes, int n_in,
                              void* d_out, int out_size, void* d_ws, size_t ws_size,
                              hipStream_t stream) {
  const int* uidx = (const int*)d_in[0];
  const int* iidx = (const int*)d_in[1];
  const int* ei_ui = (const int*)d_in[2];
  // d_in[3], d_in[4], d_in[8] (KG graph, W_r): dead code in the reference
  // (x_kg is added into x, then x is fully overwritten by relu(x_ui)).
  const float* ut = (const float*)d_in[5];
  const float* et = (const float*)d_in[6];
  const float* W = (const float*)d_in[7];

  float* out = (float*)d_out;
  float* ws = (float*)d_ws;
  unsigned* xwb = (unsigned*)(ws + XWB_OFF);
  unsigned* cnt = (unsigned*)(ws + CNT_OFF);
  float* scal = ws + SCAL_OFF;
  float* psum = ws + PSUM_OFF;
  unsigned* xwq = (unsigned*)(ws + XWQ_OFF);
  int* ssrcp = (int*)d_out;   // padded-CSR slots, aliased with out (see k_fused)

  (void)hipMemsetAsync(cnt, 0, (size_t)NN * sizeof(unsigned), stream);

  k_xw_hist<<<NXH, TPB, 0, stream>>>(uidx, iidx, ut, et, W, xwb, xwq, ei_ui,
                                     cnt, ssrcp);
  k_fused<<<NBF2, TPB, 0, stream>>>(cnt, ssrcp, xwb, xwq, out, psum);
  k_rsum<<<1, TPB, 0, stream>>>(psum, scal);
  k_scale<<<NSC, TPB, 0, stream>>>(out, scal);
}

// Round 10
// 246.289 us; speedup vs baseline: 2.8638x; 1.0685x over previous
//
#include <hip/hip_runtime.h>

#define NU 50000
#define NE 100000
#define NN 150000          // NU + NE
#define DD 64
#define EUI 1500000
#define SPLIT 75008        // node split (16-aligned): A = [0,SPLIT), B = [SPLIT,NN)

#define TPB 256
#define NBLK 2048          // edge-stride hist block count (per half)
#define NXB 2344           // ceil(NN/64) xw tiles
#define NXH (NXB + NBLK)   // launch1 grid: GEMM tiles + histA stripes
#define NBFA 4688          // SPLIT/16 fusedA tiles
#define NBFB 4687          // (NN-SPLIT)/16 fusedB tiles
#define NHF (NBFA + NBLK)  // launch2 grid: histB stripes + fusedA tiles
#define NBF2 9375          // NN/16 total fused tiles (psum size)
#define NSC 9375           // NN*DD/4/256: k_scale blocks (exact)

// workspace layout (units: 4-byte words)
#define XWB_OFF    0ull          // 4,800,000 words: xW in bf16 (row = 32 dwords)
#define CNT_OFF    4800000ull    // 150,000 u32: per-node degree (atomic rank)
#define SCAL_OFF   4950000ull    // [0] = sum(exp(logits))
#define PSUM_OFF   4950004ull    // 9,375 f32 block partials
#define XWQ_OFF    4959424ull    // 2,400,000 words: xW in q7e4 (row = 16 dwords)
                                 // byte addr % 64 == 0: one row = ONE cache line
// Padded-CSR src slots live in d_out: node n's 64 int slots occupy exactly the
// 256 bytes of out row n. k_fused reads its own slots, then overwrites them
// with the result row. Degrees are Binomial(1.5M, 1/150K): mean 10,
// P(deg>=64) ~ e^-150 -> the 64-slot stripe never overflows (guarded anyway).
// ROUND-4 LESSON: persistent cooperative fused+scale = 431 us (occupancy cap
// + ~115 us coop-launch overhead). Keep normal wide launches.
// ROUND-8 LESSON: 9375 same-address device atomicAdd(scal) serialize at ~53ns
// each (503 us). Per-block results -> psum[] array + k_rsum.
// ROUNDS 6/9 LESSON (transaction model): 2->4 edge ILP = neutral; halving
// gather LINES (q7e4, 1-line rows) = neutral. Both walls sit at the chip-wide
// random-transaction rate ~25-30/ns: hist = 3M trans ~ 100us, fused = 3-4M
// trans ~ 120us. Round-10 attacks COUNT (int4 slot loads: 4x fewer slot
// transactions) and CONCURRENCY (split-graph: histB || fusedA in one dispatch
// -- tests whether RMW/store and gather-read transactions share one pipe).
// q7e4 (7-bit mantissa, shared 4-bit exp) retained: passes absmax with 2.2x
// margin (1.86e-8 vs 4.14e-8); fp8 e4m3 failed by 1.35x (round 7).

// f32 -> bf16 RNE pack of two values into one dword (a = low/even dim)
__device__ __forceinline__ unsigned bfpack(float a, float b) {
  unsigned ua = __float_as_uint(a);
  ua = (ua + 0x7fffu + ((ua >> 16) & 1u)) >> 16;
  unsigned ub = __float_as_uint(b);
  ub = (ub + 0x7fffu + ((ub >> 16) & 1u)) & 0xffff0000u;
  return (ua & 0xffffu) | ub;
}

// ---- q7e4: 4 values -> 4x7-bit two's-complement mantissa + 4-bit shared exp.
__device__ __forceinline__ unsigned q7pack4(float a, float b, float c, float d) {
  const float m = fmaxf(fmaxf(fabsf(a), fabsf(b)), fmaxf(fabsf(c), fabsf(d)));
  int E = -20;
  if (m >= 3.0517578125e-05f) {
    E = (int)((__float_as_uint(m) >> 23) & 0xffu) - 132;  // ilogb(m) - 5
    E = max(-20, min(-5, E));
  }
  const float s = __uint_as_float((unsigned)(127 - E) << 23);  // 2^-E
  const int qa = max(-64, min(63, (int)rintf(a * s)));
  const int qb = max(-64, min(63, (int)rintf(b * s)));
  const int qc = max(-64, min(63, (int)rintf(c * s)));
  const int qd = max(-64, min(63, (int)rintf(d * s)));
  return ((unsigned)(E + 20) << 28) |
         (unsigned)(qa & 0x7f) | ((unsigned)(qb & 0x7f) << 7) |
         ((unsigned)(qc & 0x7f) << 14) | ((unsigned)(qd & 0x7f) << 21);
}

// decode: raw integer mantissas + shared scale (caller folds s: 2 muls not 4)
__device__ __forceinline__ void q7unpack4(unsigned v, float& s, float& a,
                                          float& b, float& c, float& d) {
  s = __uint_as_float(((v >> 28) + 107u) << 23);   // 2^(field-20)
  a = (float)((int)(v << 25) >> 25);
  b = (float)((int)(v << 18) >> 25);
  c = (float)((int)(v << 11) >> 25);
  d = (float)((int)(v << 4) >> 25);
}

template <int CTRL>
__device__ __forceinline__ float dpp_add(float x) {
  int y = __builtin_amdgcn_update_dpp(0, __float_as_int(x), CTRL, 0xF, 0xF, false);
  return x + __int_as_float(y);
}
// full sum across a 16-lane DPP row
__device__ __forceinline__ float row16_sum(float x) {
  x = dpp_add<0x124>(x);  // row_ror:4
  x = dpp_add<0x128>(x);  // row_ror:8
  x = dpp_add<0xB1>(x);   // quad_perm xor1
  x = dpp_add<0x4E>(x);   // quad_perm xor2
  return x;
}

// ---- hist stripe body: rank-atomic + padded scatter for dst in [lo, hi) ----
__device__ __forceinline__ void hist_body(int idx, const int* __restrict__ ei,
                                          unsigned* __restrict__ cnt,
                                          int* __restrict__ ssrcp,
                                          int lo, int hi) {
  for (int e = idx * TPB + threadIdx.x; e < EUI; e += NBLK * TPB) {
    const int dst = ei[EUI + e];
    if (dst < lo || dst >= hi) continue;
    const int src = ei[e];
    const unsigned r = atomicAdd(&cnt[dst], 1u);
    if (r < 64u) ssrcp[((size_t)dst << 6) + r] = src;
  }
}

// ---- fused body: one 16-node tile (4 waves x 4 nodes x 16 lanes) ----
__device__ __forceinline__ void fused_tile(int tile,
                                           const unsigned* __restrict__ cnt,
                                           const int* ssrcp,
                                           const unsigned* __restrict__ xwb,
                                           const unsigned* __restrict__ xwq,
                                           float* out,
                                           float* __restrict__ psum) {
  const int lane = threadIdx.x & 63;
  const int wv = threadIdx.x >> 6;
  const int sub = lane >> 4;   // node slot 0..3 (DPP row)
  const int q = lane & 15;     // dim quad 0..15
  const int n = tile * 16 + wv * 4 + sub;
  const uint2* __restrict__ x2 = (const uint2*)xwb;  // bf16 row = 16 uint2
  const uint2 dv = x2[(size_t)n * 16 + q];
  const float vd0 = __uint_as_float(dv.x << 16);
  const float vd1 = __uint_as_float(dv.x & 0xffff0000u);
  const float vd2 = __uint_as_float(dv.y << 16);
  const float vd3 = __uint_as_float(dv.y & 0xffff0000u);
  const int deg = min((int)cnt[n], 64);
  int dmax = deg;                                   // wave-uniform max degree
  dmax = max(dmax, __shfl_xor(dmax, 16, 64));
  dmax = max(dmax, __shfl_xor(dmax, 32, 64));
  const size_t base = (size_t)n << 6;
  const int nit = (dmax + 3) >> 2;                  // 4 edges / iteration
  float a0 = 0.f, a1 = 0.f, a2 = 0.f, a3 = 0.f, wacc = 0.f;
  // ONE int4 slot prefetch per iteration (round-10: was 4 scalar loads = 4x
  // the slot transactions; the 4 slots are 16 contiguous aligned bytes).
  int4 sl = *(const int4*)(ssrcp + base);
  for (int ii = 0; ii < nit; ++ii) {
    const int it = 4 * ii;
    int s0 = sl.x, s1 = sl.y, s2 = sl.z, s3 = sl.w;
    if (ii + 1 < nit) sl = *(const int4*)(ssrcp + base + it + 4);
    const bool act0 = it < deg;
    const bool act1 = it + 1 < deg;
    const bool act2 = it + 2 < deg;
    const bool act3 = it + 3 < deg;
    if (!act0) s0 = 0;   // sanitize BEFORE gather: padding is uninitialized
    if (!act1) s1 = 0;
    if (!act2) s2 = 0;
    if (!act3) s3 = 0;
    const unsigned sv0 = xwq[(size_t)s0 * 16 + q];  // 4 independent 1-line gathers
    const unsigned sv1 = xwq[(size_t)s1 * 16 + q];
    const unsigned sv2 = xwq[(size_t)s2 * 16 + q];
    const unsigned sv3 = xwq[(size_t)s3 * 16 + q];
    float se0, u0, u1, u2, u3;
    float se1, t0, t1, t2, t3;
    float se2, g0, g1, g2, g3;
    float se3, h0, h1, h2, h3;
    q7unpack4(sv0, se0, u0, u1, u2, u3);
    q7unpack4(sv1, se1, t0, t1, t2, t3);
    q7unpack4(sv2, se2, g0, g1, g2, g3);
    q7unpack4(sv3, se3, h0, h1, h2, h3);
    float p0 = vd0 * u0;
    p0 = fmaf(vd1, u1, p0); p0 = fmaf(vd2, u2, p0); p0 = fmaf(vd3, u3, p0);
    float p1 = vd0 * t0;
    p1 = fmaf(vd1, t1, p1); p1 = fmaf(vd2, t2, p1); p1 = fmaf(vd3, t3, p1);
    float p2 = vd0 * g0;
    p2 = fmaf(vd1, g1, p2); p2 = fmaf(vd2, g2, p2); p2 = fmaf(vd3, g3, p2);
    float p3 = vd0 * h0;
    p3 = fmaf(vd1, h1, p3); p3 = fmaf(vd2, h2, p3); p3 = fmaf(vd3, h3, p3);
    p0 *= se0;
    p1 *= se1;
    p2 *= se2;
    p3 *= se3;
    p0 = row16_sum(p0);
    p1 = row16_sum(p1);
    p2 = row16_sum(p2);
    p3 = row16_sum(p3);
    const float l0 = (p0 > 0.f) ? p0 : 0.2f * p0;
    const float l1 = (p1 > 0.f) ? p1 : 0.2f * p1;
    const float l2 = (p2 > 0.f) ? p2 : 0.2f * p2;
    const float l3 = (p3 > 0.f) ? p3 : 0.2f * p3;
    float w0 = __expf(l0);
    float w1 = __expf(l1);
    float w2 = __expf(l2);
    float w3 = __expf(l3);
    if (!act0) w0 = 0.f;
    if (!act1) w1 = 0.f;
    if (!act2) w2 = 0.f;
    if (!act3) w3 = 0.f;
    const float ws0 = w0 * se0;
    const float ws1 = w1 * se1;
    const float ws2 = w2 * se2;
    const float ws3 = w3 * se3;
    a0 = fmaf(ws0, u0, a0); a1 = fmaf(ws0, u1, a1);
    a2 = fmaf(ws0, u2, a2); a3 = fmaf(ws0, u3, a3);
    a0 = fmaf(ws1, t0, a0); a1 = fmaf(ws1, t1, a1);
    a2 = fmaf(ws1, t2, a2); a3 = fmaf(ws1, t3, a3);
    a0 = fmaf(ws2, g0, a0); a1 = fmaf(ws2, g1, a1);
    a2 = fmaf(ws2, g2, a2); a3 = fmaf(ws2, g3, a3);
    a0 = fmaf(ws3, h0, a0); a1 = fmaf(ws3, h1, a1);
    a2 = fmaf(ws3, h2, a2); a3 = fmaf(ws3, h3, a3);
    wacc += (w0 + w1) + (w2 + w3);
  }
  float4 r = {a0, a1, a2, a3};
  ((float4*)(out + (size_t)n * DD))[q] = r;   // overwrites this node's slots
  __shared__ float sm[16];
  if (q == 0) sm[wv * 4 + sub] = wacc;
  __syncthreads();
  if (threadIdx.x == 0) {
    float s = 0.f;
#pragma unroll
    for (int i = 0; i < 16; ++i) s += sm[i];
    psum[tile] = s;
  }
}

// ---------------- launch 1: xW GEMM + histA (dst < SPLIT) --------------------
__global__ __launch_bounds__(TPB) void k_xw_histA(const int* __restrict__ uidx,
                                                  const int* __restrict__ iidx,
                                                  const float* __restrict__ ut,
                                                  const float* __restrict__ et,
                                                  const float* __restrict__ W,
                                                  unsigned* __restrict__ xwb,
                                                  unsigned* __restrict__ xwq,
                                                  const int* __restrict__ ei,
                                                  unsigned* __restrict__ cnt,
                                                  int* __restrict__ ssrcp) {
  const int bi = blockIdx.x;
  int idx;
  bool hist;
  if (bi < 2 * NBLK) { hist = (bi & 1); idx = bi >> 1; }
  else               { hist = false;    idx = bi - NBLK; }

  if (hist) {
    hist_body(idx, ei, cnt, ssrcp, 0, SPLIT);
    return;
  }

  // LDS-tiled 64x64x64 f32 GEMM; kc loop deliberately NOT unrolled (full
  // unroll hoisted all 64 ds_read_b128 -> VGPR 232, occupancy 10%).
  __shared__ float Ws[DD * DD];   // [k][c]
  __shared__ float Xs[64 * 68];   // [r][k], padded stride 68
  const int t = threadIdx.x;
  {
    const float4* W4 = (const float4*)W;
    float4* Ws4 = (float4*)Ws;
#pragma unroll
    for (int i = 0; i < 4; ++i) Ws4[t + i * TPB] = W4[t + i * TPB];
  }
  {
    const int rl = t >> 2, ch = t & 3;
    int row = idx * 64 + rl;
    if (row >= NN) row = NN - 1;
    const float4* s4 = (const float4*)((row < NU)
        ? ut + (size_t)uidx[row] * DD
        : et + (size_t)iidx[row - NU] * DD);
    float4* x4 = (float4*)(Xs + rl * 68);
#pragma unroll
    for (int j = 0; j < 4; ++j) x4[ch + 4 * j] = s4[ch + 4 * j];
  }
  __syncthreads();
  const int q = t & 15, g = t >> 4;
  float4 acc[4] = {{0,0,0,0},{0,0,0,0},{0,0,0,0},{0,0,0,0}};
  const float* __restrict__ wsq = Ws + 4 * q;
  const float* __restrict__ xsg = Xs + (4 * g) * 68;
#pragma unroll 1
  for (int kc = 0; kc < 16; ++kc) {
    const float4 w0 = *(const float4*)(wsq + (4 * kc + 0) * DD);
    const float4 w1 = *(const float4*)(wsq + (4 * kc + 1) * DD);
    const float4 w2 = *(const float4*)(wsq + (4 * kc + 2) * DD);
    const float4 w3 = *(const float4*)(wsq + (4 * kc + 3) * DD);
#pragma unroll
    for (int i = 0; i < 4; ++i) {
      const float4 x = *(const float4*)(xsg + i * 68 + 4 * kc);
      acc[i].x = fmaf(x.x, w0.x, acc[i].x);
      acc[i].y = fmaf(x.x, w0.y, acc[i].y);
      acc[i].z = fmaf(x.x, w0.z, acc[i].z);
      acc[i].w = fmaf(x.x, w0.w, acc[i].w);
      acc[i].x = fmaf(x.y, w1.x, acc[i].x);
      acc[i].y = fmaf(x.y, w1.y, acc[i].y);
      acc[i].z = fmaf(x.y, w1.z, acc[i].z);
      acc[i].w = fmaf(x.y, w1.w, acc[i].w);
      acc[i].x = fmaf(x.z, w2.x, acc[i].x);
      acc[i].y = fmaf(x.z, w2.y, acc[i].y);
      acc[i].z = fmaf(x.z, w2.z, acc[i].z);
      acc[i].w = fmaf(x.z, w2.w, acc[i].w);
      acc[i].x = fmaf(x.w, w3.x, acc[i].x);
      acc[i].y = fmaf(x.w, w3.y, acc[i].y);
      acc[i].z = fmaf(x.w, w3.z, acc[i].z);
      acc[i].w = fmaf(x.w, w3.w, acc[i].w);
    }
  }
#pragma unroll
  for (int i = 0; i < 4; ++i) {
    const int row = idx * 64 + 4 * g + i;
    if (row < NN) {
      uint2 p;
      p.x = bfpack(acc[i].x, acc[i].y);
      p.y = bfpack(acc[i].z, acc[i].w);
      ((uint2*)(xwb + (size_t)row * 32))[q] = p;
      xwq[(size_t)row * 16 + q] = q7pack4(acc[i].x, acc[i].y, acc[i].z, acc[i].w);
    }
  }
}

// ---------------- launch 2: histB (dst >= SPLIT) || fusedA (n < SPLIT) --------
// Role-interleaved blocks. Safe: histB writes only stripes/cnt of dst>=SPLIT;
// fusedA reads stripes/cnt and writes out rows of n<SPLIT (disjoint). Tests
// whether RMW/store and gather-read transactions overlap (separate pipes) or
// serialize (shared wall) -- read this dispatch's duration vs its parts.
__global__ __launch_bounds__(TPB) void k_histB_fusedA(const int* __restrict__ ei,
                                                      unsigned* __restrict__ cnt,
                                                      int* ssrcp,
                                                      const unsigned* __restrict__ xwb,
                                                      const unsigned* __restrict__ xwq,
                                                      float* out,
                                                      float* __restrict__ psum) {
  const int bi = blockIdx.x;
  int idx;
  bool hist;
  if (bi < 2 * NBLK) { hist = (bi & 1); idx = bi >> 1; }
  else               { hist = false;    idx = bi - NBLK; }

  if (hist) {
    hist_body(idx, ei, cnt, ssrcp, SPLIT, NN);
    return;
  }
  fused_tile(idx, cnt, ssrcp, xwb, xwq, out, psum);   // tiles 0..NBFA-1
}

// ---------------- launch 3: fusedB (n >= SPLIT) -------------------------------
__global__ __launch_bounds__(TPB) void k_fusedB(const unsigned* __restrict__ cnt,
                                                const int* ssrcp,
                                                const unsigned* __restrict__ xwb,
                                                const unsigned* __restrict__ xwq,
                                                float* out,
                                                float* __restrict__ psum) {
  fused_tile(NBFA + blockIdx.x, cnt, ssrcp, xwb, xwq, out, psum);
}

// ---------------- total exp-sum -----------------------------------------------
__global__ __launch_bounds__(TPB) void k_rsum(const float* __restrict__ psum,
                                              float* __restrict__ scal) {
  float s = 0.f;
  for (int i = threadIdx.x; i < NBF2; i += TPB) s += psum[i];
#pragma unroll
  for (int off = 32; off; off >>= 1) s += __shfl_xor(s, off, 64);
  __shared__ float sm[4];
  if ((threadIdx.x & 63) == 0) sm[threadIdx.x >> 6] = s;
  __syncthreads();
  if (threadIdx.x == 0) scal[0] = sm[0] + sm[1] + sm[2] + sm[3];
}

// ---------------- out = relu(out / sumexp) ------------------------------------
__global__ __launch_bounds__(TPB) void k_scale(float* __restrict__ out,
                                               const float* __restrict__ scal) {
  const float inv = 1.0f / scal[0];
  const int i = blockIdx.x * TPB + threadIdx.x;
  float4* o4 = (float4*)out;
  float4 v = o4[i];
  v.x = fmaxf(v.x * inv, 0.f);
  v.y = fmaxf(v.y * inv, 0.f);
  v.z = fmaxf(v.z * inv, 0.f);
  v.w = fmaxf(v.w * inv, 0.f);
  o4[i] = v;
}

extern "C" void kernel_launch(void* const* d_in, const int* in_sizes, int n_in,
                              void* d_out, int out_size, void* d_ws, size_t ws_size,
                              hipStream_t stream) {
  const int* uidx = (const int*)d_in[0];
  const int* iidx = (const int*)d_in[1];
  const int* ei_ui = (const int*)d_in[2];
  // d_in[3], d_in[4], d_in[8] (KG graph, W_r): dead code in the reference
  // (x_kg is added into x, then x is fully overwritten by relu(x_ui)).
  const float* ut = (const float*)d_in[5];
  const float* et = (const float*)d_in[6];
  const float* W = (const float*)d_in[7];

  float* out = (float*)d_out;
  float* ws = (float*)d_ws;
  unsigned* xwb = (unsigned*)(ws + XWB_OFF);
  unsigned* cnt = (unsigned*)(ws + CNT_OFF);
  float* scal = ws + SCAL_OFF;
  float* psum = ws + PSUM_OFF;
  unsigned* xwq = (unsigned*)(ws + XWQ_OFF);
  int* ssrcp = (int*)d_out;   // padded-CSR slots, aliased with out

  (void)hipMemsetAsync(cnt, 0, (size_t)NN * sizeof(unsigned), stream);

  k_xw_histA<<<NXH, TPB, 0, stream>>>(uidx, iidx, ut, et, W, xwb, xwq, ei_ui,
                                      cnt, ssrcp);
  k_histB_fusedA<<<NHF, TPB, 0, stream>>>(ei_ui, cnt, ssrcp, xwb, xwq, out, psum);
  k_fusedB<<<NBFB, TPB, 0, stream>>>(cnt, ssrcp, xwb, xwq, out, psum);
  k_rsum<<<1, TPB, 0, stream>>>(psum, scal);
  k_scale<<<NSC, TPB, 0, stream>>>(out, scal);
}